// Round 9
// baseline (2146.063 us; speedup 1.0000x reference)
//
#include <hip/hip_runtime.h>

typedef unsigned short u16;
typedef unsigned long long u64;
typedef __bf16 bf16x8 __attribute__((ext_vector_type(8)));
typedef float f32x4 __attribute__((ext_vector_type(4)));

#define T_STEPS 128
#define NB 256
#define HDIM 512
#define DIN_ 255
#define PACK_ 517
#define TN 32768  // T_STEPS*NB

__device__ __forceinline__ float b2f(u16 u) {
    union { unsigned int i; float f; } v; v.i = ((unsigned int)u) << 16; return v.f;
}
__device__ __forceinline__ u16 f2b(float f) {
    union { float f; unsigned int i; } v; v.f = f;
    unsigned int r = v.i + 0x7FFFu + ((v.i >> 16) & 1u);
    return (u16)(r >> 16);
}
__device__ __forceinline__ float sigm(float x) { return 1.f / (1.f + __expf(-x)); }
__device__ __forceinline__ float ftanh(float x) { return 2.f * sigm(2.f * x) - 1.f; }

// plain (cached) 16B load; vmcnt tracked manually via WAIT macros.
__device__ __forceinline__ bf16x8 ldx4(const u16* p) {
    f32x4 t;
    asm volatile("global_load_dwordx4 %0, %1, off" : "=v"(t) : "v"(p) : "memory");
    union { f32x4 f; bf16x8 b; } u; u.f = t; return u.b;
}
#define WAIT_VMCNT(N) asm volatile("s_waitcnt vmcnt(" #N ")" ::: "memory")
#define WAIT_LGKM0    asm volatile("s_waitcnt lgkmcnt(0)" ::: "memory")

// C[M x N] = act(A @ B^T + bias); B panel (64 x K) staged in LDS fragment-major.
// skip: device flag — if *skip==128 the persistent workers already did this work.
template<int DO_TANH, int K, int MT>
__global__ __launch_bounds__(256) void gemm_bt(const u16* __restrict__ A,
                                               const u16* __restrict__ B,
                                               const float* __restrict__ bias,
                                               u16* __restrict__ C, int N,
                                               const unsigned* __restrict__ skip) {
    if (skip && *skip == 128u) return;
    __shared__ u16 lds[64 * K];  // frag(row,kq) at u16 idx (kq*64+row)*8
    int n0 = blockIdx.x * 64;
    int w = threadIdx.x >> 6, l = threadIdx.x & 63;
    int la = l & 15, lb = l >> 4;
    for (int idx = threadIdx.x; idx < 8 * K; idx += 256) {
        int kq = idx >> 6, row = idx & 63;
        *(bf16x8*)(lds + (size_t)idx * 8) =
            *(const bf16x8*)(B + (size_t)(n0 + row) * K + kq * 8);
    }
    __syncthreads();
    const u16* bq[4];
    #pragma unroll
    for (int c = 0; c < 4; ++c) bq[c] = lds + ((size_t)lb * 64 + 16 * c + la) * 8;

    for (int mt = 0; mt < MT; ++mt) {
        int m0 = (blockIdx.y * MT + mt) * 64;
        int mw = m0 + 16 * w;
        const u16* Ap = A + (size_t)(mw + la) * K + 8 * lb;
        f32x4 acc[4] = {};
        #pragma unroll
        for (int k0 = 0; k0 < K; k0 += 32) {
            bf16x8 a = *(const bf16x8*)(Ap + k0);
            #pragma unroll
            for (int c = 0; c < 4; ++c)
                acc[c] = __builtin_amdgcn_mfma_f32_16x16x32_bf16(
                    a, *(const bf16x8*)(bq[c] + (size_t)k0 * 64), acc[c], 0, 0, 0);
        }
        #pragma unroll
        for (int c = 0; c < 4; ++c) {
            int n = n0 + 16 * c + la;
            float bv = bias[n];
            #pragma unroll
            for (int r = 0; r < 4; ++r) {
                int m = mw + 4 * lb + r;
                float v = acc[c][r] + bv;
                if (DO_TANH) v = ftanh(v);
                C[(size_t)m * N + n] = f2b(v);
            }
        }
    }
}

// Persistent GRU recurrence (WGs 0..127, byte-identical sync to R7/R8) +
// WORKER WGs 128..255: R8 proved heaters (37.8% VALUBusy) don't move the
// ~8.7us/step floor -> stop fighting it; reclaim the idle half-chip to run the
// ENTIRE MLP epilogue (expand_h, actor/critic MLPs, heads, finalize, tail)
// chasing the recurrence. Worker j serves group g=j&7 (same XCD under
// round-robin, runtime-verified), items t = (j>>3)+16*it. Engagement decided by
// an all-or-nothing vote; the epilogue kernels early-exit ONLY if all 128
// workers finished clean (wfin==128) -> any anomaly falls back to the old path.
__global__ __launch_bounds__(256, 1) void gru_persist(
    const u16* __restrict__ h0b, const float* __restrict__ hx,
    const u16* __restrict__ whh_b, const float* __restrict__ bhh,
    const u16* __restrict__ gi_b,
    u16* __restrict__ hs_b, unsigned int* __restrict__ bar,
    const u16* __restrict__ wa0_b, const float* __restrict__ ba0,
    const u16* __restrict__ wa1_b, const float* __restrict__ ba1,
    const u16* __restrict__ wloc_b, const float* __restrict__ bloc,
    const u16* __restrict__ wc0_b, const float* __restrict__ bc0,
    const u16* __restrict__ wc1_b, const float* __restrict__ bc1,
    const u16* __restrict__ wv_b, const float* __restrict__ bv,
    float* __restrict__ out, const float* __restrict__ eps,
    const float* __restrict__ inputs, const float* __restrict__ logstd) {
    extern __shared__ u16 lds[];
    __shared__ unsigned s_locv;
    __shared__ unsigned s_eng;
    __shared__ int s_ok;
    const int tid = threadIdx.x;
    const int bid = blockIdx.x;
    const int w = tid >> 6, l = tid & 63;
    const int la = l & 15, lb = l >> 4;
    unsigned int* wyes = bar + 8576;
    unsigned int* wno  = bar + 8592;
    unsigned int* wfin = bar + 8608;
    unsigned int* tbl  = bar + 8192;  // 128 write-once XCD entries

    unsigned myx;
    asm volatile("s_getreg_b32 %0, hwreg(HW_REG_XCC_ID)" : "=s"(myx));
    myx = (myx & 15u) + 1u;

    if (bid >= 128) {
        // ================= WORKER ROLE =================
        const int j = bid - 128;
        const int g = j & 7;
        // verdict: group placed, uniform XCD, and equals MY xcd
        if (tid == 0) {
            unsigned vals[16];
            int guard = 0; bool ok;
            do {
                ok = true;
                #pragma unroll
                for (int k = 0; k < 16; ++k) {
                    vals[k] = __hip_atomic_fetch_add(tbl + g + 8 * k, 0u,
                                                     __ATOMIC_RELAXED,
                                                     __HIP_MEMORY_SCOPE_AGENT);
                    ok = ok && (vals[k] != 0u);
                }
                if (!ok) __builtin_amdgcn_s_sleep(8);
            } while (!ok && ++guard < (1 << 16));
            unsigned lv = ok ? 1u : 0u;
            #pragma unroll
            for (int k = 0; k < 16; ++k) lv &= (unsigned)(vals[k] == myx);
            __hip_atomic_fetch_add(lv ? wyes : wno, 1u, __ATOMIC_RELAXED,
                                   __HIP_MEMORY_SCOPE_AGENT);
            guard = 0;
            unsigned y, n;
            for (;;) {
                y = __hip_atomic_fetch_add(wyes, 0u, __ATOMIC_RELAXED,
                                           __HIP_MEMORY_SCOPE_AGENT);
                n = __hip_atomic_fetch_add(wno, 0u, __ATOMIC_RELAXED,
                                           __HIP_MEMORY_SCOPE_AGENT);
                if (y + n >= 128u || ++guard > (1 << 16)) break;
                __builtin_amdgcn_s_sleep(8);
            }
            s_eng = (n == 0u && y == 128u) ? 1u : 0u;
            s_ok = 1;
        }
        __syncthreads();
        if (!s_eng) return;

        u16* xh  = lds;            // 32x512 bf16 h tile
        u16* xt0 = lds + 16384;    // stage ping
        u16* xt1 = lds + 32768;    // stage pong
        float* hsc = (float*)(lds + 49152);  // 64 floats: loc[32], v[32]

        for (int it = 0; it < 8; ++it) {
            const int t = (j >> 3) + 16 * it;
            // wait for group's h[t]: all 16 flags >= t+1 (loc-path L2 atomics)
            if (w == 0) {
                unsigned int* pl = bar + (g * 16 + (l & 15)) * 64;
                int guard = 0;
                for (;;) {
                    bool okl = true;
                    if (l < 16) {
                        unsigned v;
                        asm volatile("global_atomic_add %0, %1, %2, off sc0\n\t"
                                     "s_waitcnt vmcnt(0)"
                                     : "=v"(v) : "v"(pl), "v"(0u) : "memory");
                        okl = (v >= (unsigned)(t + 1));
                    }
                    if (__all(okl)) break;
                    if (++guard > (1 << 16)) { if (l == 0) s_ok = 0; break; }
                    __builtin_amdgcn_s_sleep(16);
                }
            }
            __syncthreads();
            if (!s_ok) break;

            // stage h tile (32 rows x 512, contiguous 32KB)
            const u16* hsp = hs_b + (size_t)t * NB * HDIM + (size_t)g * 32 * HDIM;
            for (int i = tid; i < 2048; i += 256)
                *(bf16x8*)(xh + (size_t)i * 8) = *(const bf16x8*)(hsp + (size_t)i * 8);
            __syncthreads();

            // one MLP GEMM stage: Y = tanh(X @ W^T + bias), 32x512, K=512.
            // Wave layout identical to gemm_bt (verified fragment mapping).
            const int rw = w & 1, ch = w >> 1;
            auto do_gemm = [&](const u16* X, const u16* Wm,
                               const float* bias, u16* Y) {
                bf16x8 a[16];
                #pragma unroll
                for (int kk = 0; kk < 16; ++kk)
                    a[kk] = *(const bf16x8*)(X + (16 * rw + la) * 512 + 8 * lb + 32 * kk);
                for (int c = 0; c < 16; ++c) {
                    int n0 = 256 * ch + 16 * c;
                    f32x4 acc = {};
                    #pragma unroll
                    for (int kk = 0; kk < 16; ++kk) {
                        bf16x8 b = *(const bf16x8*)(Wm + (size_t)(n0 + la) * 512
                                                    + 8 * lb + 32 * kk);
                        acc = __builtin_amdgcn_mfma_f32_16x16x32_bf16(a[kk], b, acc, 0, 0, 0);
                    }
                    float bvv = bias[n0 + la];
                    #pragma unroll
                    for (int r = 0; r < 4; ++r)
                        Y[(16 * rw + 4 * lb + r) * 512 + n0 + la] = f2b(ftanh(acc[r] + bvv));
                }
                __syncthreads();
            };
            // head: dst[row] = dot(X[row,:512], Wh[:512]) + bh (4 waves x 8 rows)
            auto do_head = [&](const u16* X, const u16* Wh,
                               const float* bh_, float* dst) {
                for (int rr = 0; rr < 8; ++rr) {
                    int row = 8 * w + rr;
                    bf16x8 xv = *(const bf16x8*)(X + row * 512 + 8 * l);
                    bf16x8 wv = *(const bf16x8*)(Wh + 8 * l);
                    float s2 = 0.f;
                    #pragma unroll
                    for (int q = 0; q < 8; ++q) s2 += (float)xv[q] * (float)wv[q];
                    #pragma unroll
                    for (int d = 32; d; d >>= 1) s2 += __shfl_down(s2, d, 64);
                    if (l == 0) dst[row] = s2 + bh_[0];
                }
                __syncthreads();
            };

            do_gemm(xh, wa0_b, ba0, xt0);
            do_gemm(xt0, wa1_b, ba1, xt1);
            do_head(xt1, wloc_b, bloc, hsc);
            do_gemm(xh, wc0_b, bc0, xt0);
            do_gemm(xt0, wc1_b, bc1, xt1);
            do_head(xt1, wv_b, bv, hsc + 32);

            // final packed-out writes for rows of (t,g); duplicate to tail if t==127
            const int row = tid >> 3, part = tid & 7;
            const int m = g * 32 + row;
            float* o0 = out + (size_t)(t * NB + m) * PACK_;
            float* o1 = out + (size_t)(T_STEPS * NB + m) * PACK_;
            const int kb = part * 64;
            for (int q = 0; q < 64; ++q) {
                float hv = b2f(xh[row * 512 + kb + q]);
                o0[4 + kb + q] = hv;
                if (t == T_STEPS - 1) o1[4 + kb + q] = hv;
            }
            if (part == 0) {
                float locv = hsc[row], vv2 = hsc[32 + row];
                float scale = __expf(logstd[0]);
                float act = inputs[(size_t)(t * NB + m) * 256 + DIN_];
                float a2 = (act < 0.f) ? (locv + scale * eps[t * NB + m]) : act;
                float pv = hx[(size_t)m * PACK_ + PACK_ - 1];
                o0[0] = a2; o0[1] = locv; o0[2] = scale; o0[3] = vv2;
                o0[PACK_ - 1] = pv;
                if (t == T_STEPS - 1) {
                    o1[0] = a2; o1[1] = locv; o1[2] = scale; o1[3] = vv2;
                    o1[PACK_ - 1] = pv;
                }
            }
            __syncthreads();  // xh/xt reuse next item
        }
        if (tid == 0 && s_ok)
            __hip_atomic_fetch_add(wfin, 1u, __ATOMIC_RELAXED,
                                   __HIP_MEMORY_SCOPE_AGENT);
        return;
    }

    // ================= SYNC/COMPUTE ROLE (R7/R8-proven) =================
    const int g = bid & 7, s = bid >> 3;
    const int ks = s * 32, m0 = g * 32;
    const int rw = w >> 1, cw = w & 1;
    const int mw = m0 + 16 * rw;
    const int kc = ks + 16 * cw;

    if (tid == 0)
        __hip_atomic_fetch_add(tbl + bid, myx, __ATOMIC_RELAXED,
                               __HIP_MEMORY_SCOPE_AGENT);

    for (int idx = tid; idx < 6144; idx += 256) {
        int kq = idx / 96, row = idx - kq * 96;
        int gg = row >> 5, rr = row & 31;
        *(bf16x8*)(lds + (size_t)idx * 8) =
            *(const bf16x8*)(whh_b + (size_t)(gg * HDIM + ks + rr) * HDIM + kq * 8);
    }
    const u16* bq[3];
    #pragma unroll
    for (int c = 0; c < 3; ++c)
        bq[c] = lds + (size_t)(lb * 96 + c * 32 + 16 * cw + la) * 8;
    float bh[3];
    #pragma unroll
    for (int gg = 0; gg < 3; ++gg) bh[gg] = bhh[gg * HDIM + kc + la];
    float hp[4];
    #pragma unroll
    for (int r = 0; r < 4; ++r)
        hp[r] = hx[(size_t)(mw + 4 * lb + r) * PACK_ + 4 + kc + la];

    if (tid == 0) {
        unsigned vals[16];
        int guard = 0; bool ok;
        do {
            ok = true;
            #pragma unroll
            for (int k = 0; k < 16; ++k) {
                vals[k] = __hip_atomic_fetch_add(tbl + g + 8 * k, 0u,
                                                 __ATOMIC_RELAXED,
                                                 __HIP_MEMORY_SCOPE_AGENT);
                ok = ok && (vals[k] != 0u);
            }
            if (!ok) __builtin_amdgcn_s_sleep(8);
        } while (!ok && ++guard < (1 << 16));
        unsigned lv = ok ? 1u : 0u;
        #pragma unroll
        for (int k = 1; k < 16; ++k) lv &= (unsigned)(vals[k] == vals[0]);
        s_locv = lv;
    }
    u16* packbuf = lds + 49152 + w * 256;
    __syncthreads();
    const bool loc = (s_locv != 0);
    unsigned int* myline = bar + (g * 16 + s) * 64;
    unsigned int* pline  = bar + (g * 16 + (l & 15)) * 64;

    for (int t = 0; t < T_STEPS; ++t) {
        const u16* gi_t = gi_b + (size_t)t * NB * 3 * HDIM;

        u16 giv[3][4];
        #pragma unroll
        for (int r = 0; r < 4; ++r) {
            const u16* gp = gi_t + (size_t)(mw + 4 * lb + r) * 1536 + kc + la;
            #pragma unroll
            for (int gg = 0; gg < 3; ++gg) giv[gg][r] = gp[gg * HDIM];
        }

        if (t > 0) {
            if (w == 0) {
                int guard = 0, delay = 32;
                for (;;) {
                    bool okl = true;
                    if (l < 16) {
                        unsigned v;
                        if (loc)
                            asm volatile(
                                "global_atomic_add %0, %1, %2, off sc0\n\t"
                                "s_waitcnt vmcnt(0)"
                                : "=v"(v) : "v"(pline), "v"(0u) : "memory");
                        else
                            v = __hip_atomic_fetch_add(pline, 0u, __ATOMIC_RELAXED,
                                                       __HIP_MEMORY_SCOPE_AGENT);
                        okl = ((int)v >= t);
                    }
                    if (__all(okl) || ++guard > (1 << 14)) break;
                    float z = (float)delay;
                    for (int q = 0; q < delay; ++q)
                        z = __builtin_fmaf(z, 1.0000001f, 0.0625f);
                    asm volatile("" :: "v"(z));
                    delay = delay < 2048 ? delay * 2 : 2048;
                }
            }
            __syncthreads();
            asm volatile("" ::: "memory");
        }

        const u16* Ap = (t ? hs_b + (size_t)(t - 1) * NB * HDIM : h0b)
                        + (size_t)(mw + la) * HDIM + 8 * lb;
        bf16x8 a[16];
        #pragma unroll
        for (int kk = 0; kk < 16; ++kk) a[kk] = ldx4(Ap + 32 * kk);

        f32x4 acc[3] = {};
        WAIT_VMCNT(8);
        __builtin_amdgcn_sched_barrier(0);
        #pragma unroll
        for (int kk = 0; kk < 8; ++kk) {
            #pragma unroll
            for (int c = 0; c < 3; ++c)
                acc[c] = __builtin_amdgcn_mfma_f32_16x16x32_bf16(
                    a[kk], *(const bf16x8*)(bq[c] + (size_t)kk * 3072), acc[c], 0, 0, 0);
        }
        WAIT_VMCNT(0);
        __builtin_amdgcn_sched_barrier(0);
        #pragma unroll
        for (int kk = 8; kk < 16; ++kk) {
            #pragma unroll
            for (int c = 0; c < 3; ++c)
                acc[c] = __builtin_amdgcn_mfma_f32_16x16x32_bf16(
                    a[kk], *(const bf16x8*)(bq[c] + (size_t)kk * 3072), acc[c], 0, 0, 0);
        }

        float hnewv[4];
        #pragma unroll
        for (int r = 0; r < 4; ++r) {
            float rr2 = sigm(b2f(giv[0][r]) + acc[0][r] + bh[0]);
            float zz  = sigm(b2f(giv[1][r]) + acc[1][r] + bh[1]);
            float nn  = ftanh(b2f(giv[2][r]) + rr2 * (acc[2][r] + bh[2]));
            float hnew = (1.f - zz) * nn + zz * hp[r];
            hp[r] = hnew;
            hnewv[r] = hnew;
        }

        #pragma unroll
        for (int r = 0; r < 4; ++r) {
            float nbv = __shfl_xor(hnewv[r], 1, 64);
            if (!(la & 1)) {
                unsigned pk = (unsigned)f2b(hnewv[r]) | ((unsigned)f2b(nbv) << 16);
                *(unsigned*)(packbuf + (4 * lb + r) * 16 + la) = pk;
            }
        }
        WAIT_LGKM0;
        __builtin_amdgcn_sched_barrier(0);
        u16* hs_t = hs_b + (size_t)t * NB * HDIM;
        if (l < 32) {
            bf16x8 hv = *(const bf16x8*)(packbuf + (l >> 1) * 16 + 8 * (l & 1));
            union { bf16x8 b; f32x4 f; } u; u.b = hv;
            u16* sp = hs_t + (size_t)(mw + (l >> 1)) * HDIM + kc + 8 * (l & 1);
            if (loc) asm volatile("global_store_dwordx4 %0, %1, off"
                                  :: "v"(sp), "v"(u.f) : "memory");
            else     asm volatile("global_store_dwordx4 %0, %1, off sc0 sc1"
                                  :: "v"(sp), "v"(u.f) : "memory");
        }
        WAIT_VMCNT(0);
        __syncthreads();
        if (tid == 0) {  // unconditional: workers need the t=127 signal too
            if (loc)
                asm volatile("global_atomic_add %0, %1, off"
                             :: "v"(myline), "v"(1u) : "memory");
            else
                __hip_atomic_fetch_add(myline, 1u, __ATOMIC_RELAXED,
                                       __HIP_MEMORY_SCOPE_AGENT);
        }
    }
}

// fallback epilogue kernels (skipped when the persistent workers did the work)
__global__ void expand_h(const u16* __restrict__ hs, float* __restrict__ out,
                         const unsigned* __restrict__ skip) {
    if (*skip == 128u) return;
    int idx = blockIdx.x * 256 + threadIdx.x;
    if (idx >= TN * 256) return;
    int m = idx >> 8, kk = (idx & 255) * 2;
    unsigned pk = *(const unsigned*)(hs + (size_t)m * HDIM + kk);
    float* o = out + (size_t)m * PACK_ + 4 + kk;
    o[0] = b2f((u16)(pk & 0xFFFFu));
    o[1] = b2f((u16)(pk >> 16));
}

__global__ __launch_bounds__(256) void head_dot(const u16* __restrict__ X,
                                                const u16* __restrict__ W,
                                                const float* __restrict__ b,
                                                float* __restrict__ out, int off,
                                                const unsigned* __restrict__ skip) {
    if (*skip == 128u) return;
    int wid = (int)((blockIdx.x * blockDim.x + threadIdx.x) >> 6);
    int l = threadIdx.x & 63;
    if (wid >= TN) return;
    bf16x8 xv = *(const bf16x8*)(X + (size_t)wid * HDIM + 8 * l);
    bf16x8 wv = *(const bf16x8*)(W + 8 * l);
    float s = 0.f;
    #pragma unroll
    for (int j = 0; j < 8; ++j) s += (float)xv[j] * (float)wv[j];
    #pragma unroll
    for (int d = 32; d; d >>= 1) s += __shfl_down(s, d, 64);
    if (l == 0) out[(size_t)wid * PACK_ + off] = s + b[0];
}

__global__ void prep_w(const float* __restrict__ Wih, const float* __restrict__ Whh,
                       const float* __restrict__ Wa0, const float* __restrict__ Wa1,
                       const float* __restrict__ Wloc, const float* __restrict__ Wc0,
                       const float* __restrict__ Wc1, const float* __restrict__ Wv,
                       const float* __restrict__ hx,
                       u16* Wih_b, u16* Whh_b, u16* Wa0_b, u16* Wa1_b,
                       u16* Wloc_b, u16* Wc0_b, u16* Wc1_b, u16* Wv_b,
                       float* h0f, u16* h0b) {
    int i = blockIdx.x * 256 + threadIdx.x;
    if (i < 1536 * 256) { int r = i >> 8, c = i & 255;
        Wih_b[i] = (c < DIN_) ? f2b(Wih[r * DIN_ + c]) : (u16)0; return; }
    i -= 1536 * 256;
    if (i < 1536 * 512) { Whh_b[i] = f2b(Whh[i]); return; } i -= 1536 * 512;
    if (i < 512 * 512) { Wa0_b[i] = f2b(Wa0[i]); return; } i -= 512 * 512;
    if (i < 512 * 512) { Wa1_b[i] = f2b(Wa1[i]); return; } i -= 512 * 512;
    if (i < 512 * 512) { Wc0_b[i] = f2b(Wc0[i]); return; } i -= 512 * 512;
    if (i < 512 * 512) { Wc1_b[i] = f2b(Wc1[i]); return; } i -= 512 * 512;
    if (i < 512) { Wloc_b[i] = f2b(Wloc[i]); return; } i -= 512;
    if (i < 512) { Wv_b[i] = f2b(Wv[i]); return; } i -= 512;
    if (i < NB * HDIM) { int n = i >> 9, k = i & 511;
        float v = hx[n * PACK_ + 4 + k]; h0f[i] = v; h0b[i] = f2b(v); return; }
}

__global__ void prep_obs(const float* __restrict__ in, u16* __restrict__ obs) {
    int idx = blockIdx.x * 256 + threadIdx.x;
    if (idx >= TN * 32) return;
    int m = idx >> 5, j = idx & 31;
    const float* src = in + (size_t)m * 256 + 8 * j;
    union { u16 s[8]; uint4 u; } t;
    #pragma unroll
    for (int q = 0; q < 8; ++q) t.s[q] = f2b(src[q]);
    if (j == 31) t.s[7] = 0;  // d=255 is the actions column
    *(uint4*)(obs + (size_t)m * 256 + 8 * j) = t.u;
}

__global__ void finalize_out(const float* __restrict__ in, const float* __restrict__ eps,
                             const float* __restrict__ hx, const float* __restrict__ logstd,
                             float* __restrict__ out,
                             const unsigned* __restrict__ skip) {
    if (*skip == 128u) return;
    int m = blockIdx.x * 256 + threadIdx.x;
    if (m >= TN) return;
    int n = m & (NB - 1);
    float scale = __expf(logstd[0]);
    float loc = out[(size_t)m * PACK_ + 1];
    float act = in[(size_t)m * 256 + DIN_];
    float a = (act < 0.f) ? (loc + scale * eps[m]) : act;
    out[(size_t)m * PACK_ + 0] = a;
    out[(size_t)m * PACK_ + 2] = scale;
    out[(size_t)m * PACK_ + PACK_ - 1] = hx[n * PACK_ + PACK_ - 1];
}

__global__ void tail_copy(float* __restrict__ out, const unsigned* __restrict__ skip) {
    if (*skip == 128u) return;
    int i = blockIdx.x * 256 + threadIdx.x;
    if (i >= NB * PACK_) return;
    out[(size_t)T_STEPS * NB * PACK_ + i] = out[(size_t)(T_STEPS - 1) * NB * PACK_ + i];
}

extern "C" void kernel_launch(void* const* d_in, const int* in_sizes, int n_in,
                              void* d_out, int out_size, void* d_ws, size_t ws_size,
                              hipStream_t stream) {
    const float* inputs = (const float*)d_in[0];
    const float* hx     = (const float*)d_in[1];
    const float* eps    = (const float*)d_in[2];
    const float* Wih    = (const float*)d_in[3];
    const float* Whh    = (const float*)d_in[4];
    const float* bih    = (const float*)d_in[5];
    const float* bhh    = (const float*)d_in[6];
    const float* Wa0    = (const float*)d_in[7];
    const float* ba0    = (const float*)d_in[8];
    const float* Wa1    = (const float*)d_in[9];
    const float* ba1    = (const float*)d_in[10];
    const float* Wloc   = (const float*)d_in[11];
    const float* bloc   = (const float*)d_in[12];
    const float* logstd = (const float*)d_in[13];
    const float* Wc0    = (const float*)d_in[14];
    const float* bc0    = (const float*)d_in[15];
    const float* Wc1    = (const float*)d_in[16];
    const float* bc1    = (const float*)d_in[17];
    const float* Wv     = (const float*)d_in[18];
    const float* bv     = (const float*)d_in[19];
    float* out = (float*)d_out;
    char* ws = (char*)d_ws;

    const size_t o_gi   = 0;
    const size_t o_buf0 = 0;
    const size_t o_buf1 = 33554432;
    const size_t o_hs   = 100663296;
    const size_t o_obs  = o_hs + 33554432;
    const size_t o_whh  = o_obs + 16777216;
    const size_t o_wih  = o_whh + 1572864;
    const size_t o_wa0  = o_wih + 786432;
    const size_t o_wa1  = o_wa0 + 524288;
    const size_t o_wc0  = o_wa1 + 524288;
    const size_t o_wc1  = o_wc0 + 524288;
    const size_t o_wloc = o_wc1 + 524288;
    const size_t o_wv   = o_wloc + 1024;
    const size_t o_h0f  = o_wv + 1024;
    const size_t o_h0b  = o_h0f + 524288;
    const size_t o_bar  = o_h0b + 262144;
    const size_t NEED   = o_bar + 36864;
    if (ws_size < NEED) return;

    u16*   gi_b   = (u16*)(ws + o_gi);
    u16*   buf0   = (u16*)(ws + o_buf0);
    u16*   buf1   = (u16*)(ws + o_buf1);
    u16*   hs_b   = (u16*)(ws + o_hs);
    u16*   obs_b  = (u16*)(ws + o_obs);
    u16*   whh_b  = (u16*)(ws + o_whh);
    u16*   wih_b  = (u16*)(ws + o_wih);
    u16*   wa0_b  = (u16*)(ws + o_wa0);
    u16*   wa1_b  = (u16*)(ws + o_wa1);
    u16*   wc0_b  = (u16*)(ws + o_wc0);
    u16*   wc1_b  = (u16*)(ws + o_wc1);
    u16*   wloc_b = (u16*)(ws + o_wloc);
    u16*   wv_b   = (u16*)(ws + o_wv);
    float* h0f    = (float*)(ws + o_h0f);
    u16*   h0b    = (u16*)(ws + o_h0b);
    unsigned int* bar = (unsigned int*)(ws + o_bar);
    const unsigned* wfin = (const unsigned*)(ws + o_bar + 8608 * 4);

    static bool attr_set = false;
    if (!attr_set) {
        hipFuncSetAttribute((const void*)gru_persist,
                            hipFuncAttributeMaxDynamicSharedMemorySize, 102400);
        attr_set = true;
    }

    hipMemsetAsync(bar, 0, 36864, stream);  // flags/tbl/votes/wfin zeroed

    prep_w<<<9220, 256, 0, stream>>>(Wih, Whh, Wa0, Wa1, Wloc, Wc0, Wc1, Wv, hx,
                                     wih_b, whh_b, wa0_b, wa1_b, wloc_b, wc0_b, wc1_b, wv_b,
                                     h0f, h0b);
    prep_obs<<<4096, 256, 0, stream>>>(inputs, obs_b);

    // gi = obs_pad @ Wih_pad^T + bih   (never skipped)
    gemm_bt<0, 256, 8><<<dim3(24, 64), 256, 0, stream>>>(obs_b, wih_b, bih, gi_b,
                                                         1536, nullptr);

    // persistent recurrence (128 sync WGs) + MLP workers (128 WGs)
    gru_persist<<<256, 256, 102400, stream>>>(
        h0b, hx, whh_b, bhh, gi_b, hs_b, bar,
        wa0_b, ba0, wa1_b, ba1, wloc_b, bloc,
        wc0_b, bc0, wc1_b, bc1, wv_b, bv,
        out, eps, inputs, logstd);

    // fallback epilogue (skips itself when workers completed: *wfin==128)
    expand_h<<<32768, 256, 0, stream>>>(hs_b, out, wfin);
    gemm_bt<1, 512, 8><<<dim3(8, 64), 256, 0, stream>>>(hs_b, wa0_b, ba0, buf0, 512, wfin);
    gemm_bt<1, 512, 8><<<dim3(8, 64), 256, 0, stream>>>(buf0, wa1_b, ba1, buf1, 512, wfin);
    head_dot<<<8192, 256, 0, stream>>>(buf1, wloc_b, bloc, out, 1, wfin);
    gemm_bt<1, 512, 8><<<dim3(8, 64), 256, 0, stream>>>(hs_b, wc0_b, bc0, buf0, 512, wfin);
    gemm_bt<1, 512, 8><<<dim3(8, 64), 256, 0, stream>>>(buf0, wc1_b, bc1, buf1, 512, wfin);
    head_dot<<<8192, 256, 0, stream>>>(buf1, wv_b, bv, out, 3, wfin);
    finalize_out<<<128, 256, 0, stream>>>(inputs, eps, hx, logstd, out, wfin);
    tail_copy<<<518, 256, 0, stream>>>(out, wfin);
}